// Round 1
// baseline (3720.486 us; speedup 1.0000x reference)
//
#include <hip/hip_runtime.h>
#include <hip/hip_bf16.h>
#include <math.h>

// Problem: cross-attention forward.
//   B=32, LQ=64, LKV=4096, D=512, all fp32.
//   q = x1@wq^T+bq; k = x2@wk^T+bk; v = x2@wv^T+bv
//   s = (q@k^T) * sqrt(512)   (reference DIVIDES by d^-0.5)
//   p = softmax(s, axis=-1);  out = p@v
// Round 0: all-fp32 vector-ALU baseline (no MFMA — scores need ~fp32 accuracy
// because the sqrt(d) MULTIPLY makes softmax near-argmax; bf16 q/k would flip
// near-tied rows). Materializes q,k,v,s in d_ws: needs ~548 MiB of workspace.

#define DM 512           // model dim
#define LQ 64
#define LKV 4096
#define NB 32            // batches
#define SCALE 22.627416997969522f   // sqrt(512)

// ---------------- generic linear: Y[R,512] = X[R,512] @ W^T + bias ----------
// grid: (R/128, 512/128), block 256, 8x8 microtile, BK=16
__global__ __launch_bounds__(256) void linear_bt(const float* __restrict__ X,
                                                 const float* __restrict__ W,
                                                 const float* __restrict__ bias,
                                                 float* __restrict__ Y) {
    __shared__ float xs[128][17];
    __shared__ float ws_[128][17];
    const int bm = blockIdx.x, bn = blockIdx.y;
    const int t  = threadIdx.x;
    const int tx = t & 15, ty = t >> 4;

    const float* Xb = X + (size_t)bm * 128 * DM;
    const float* Wb = W + (size_t)bn * 128 * DM;

    float acc[8][8];
#pragma unroll
    for (int i = 0; i < 8; ++i)
#pragma unroll
        for (int j = 0; j < 8; ++j) acc[i][j] = 0.f;

    const int lr = t >> 1;           // 0..127
    const int lc = (t & 1) << 3;     // 0 or 8

    for (int k0 = 0; k0 < DM; k0 += 16) {
        const float* xp = Xb + (size_t)lr * DM + k0 + lc;
        const float* wp = Wb + (size_t)lr * DM + k0 + lc;
        float4 x0 = *(const float4*)(xp);
        float4 x1 = *(const float4*)(xp + 4);
        float4 w0 = *(const float4*)(wp);
        float4 w1 = *(const float4*)(wp + 4);
        xs[lr][lc+0]=x0.x; xs[lr][lc+1]=x0.y; xs[lr][lc+2]=x0.z; xs[lr][lc+3]=x0.w;
        xs[lr][lc+4]=x1.x; xs[lr][lc+5]=x1.y; xs[lr][lc+6]=x1.z; xs[lr][lc+7]=x1.w;
        ws_[lr][lc+0]=w0.x; ws_[lr][lc+1]=w0.y; ws_[lr][lc+2]=w0.z; ws_[lr][lc+3]=w0.w;
        ws_[lr][lc+4]=w1.x; ws_[lr][lc+5]=w1.y; ws_[lr][lc+6]=w1.z; ws_[lr][lc+7]=w1.w;
        __syncthreads();
#pragma unroll
        for (int kk = 0; kk < 16; ++kk) {
            float a[8], b[8];
#pragma unroll
            for (int i = 0; i < 8; ++i) a[i] = xs[ty*8+i][kk];
#pragma unroll
            for (int j = 0; j < 8; ++j) b[j] = ws_[tx*8+j][kk];
#pragma unroll
            for (int i = 0; i < 8; ++i)
#pragma unroll
                for (int j = 0; j < 8; ++j) acc[i][j] = fmaf(a[i], b[j], acc[i][j]);
        }
        __syncthreads();
    }
#pragma unroll
    for (int i = 0; i < 8; ++i) {
        size_t row = (size_t)bm * 128 + ty*8 + i;
#pragma unroll
        for (int j = 0; j < 8; ++j) {
            int col = bn*128 + tx*8 + j;
            Y[row * DM + col] = acc[i][j] + bias[col];
        }
    }
}

// ---------------- scores: S[b,i,j] = sqrt(512) * q[b,i,:]·k[b,j,:] ----------
// grid: (NB, LKV/128), block 256, 4x8 microtile, BK=16
__global__ __launch_bounds__(256) void qk_kernel(const float* __restrict__ Q,
                                                 const float* __restrict__ K,
                                                 float* __restrict__ S) {
    __shared__ float qs[64][17];
    __shared__ float ks[128][17];
    const int b = blockIdx.x, jt = blockIdx.y;
    const int t = threadIdx.x;
    const int tx = t & 15, ty = t >> 4;

    const float* Qb = Q + (size_t)b * LQ * DM;
    const float* Kb = K + (size_t)b * LKV * DM + (size_t)jt * 128 * DM;

    float acc[4][8];
#pragma unroll
    for (int i = 0; i < 4; ++i)
#pragma unroll
        for (int j = 0; j < 8; ++j) acc[i][j] = 0.f;

    const int qr = t >> 2, qc = (t & 3) << 2;   // 64 rows x 16 cols, float4 each
    const int kr = t >> 1, kc = (t & 1) << 3;   // 128 rows x 16 cols, 8 floats each

    for (int k0 = 0; k0 < DM; k0 += 16) {
        float4 qv = *(const float4*)(Qb + (size_t)qr * DM + k0 + qc);
        qs[qr][qc+0]=qv.x; qs[qr][qc+1]=qv.y; qs[qr][qc+2]=qv.z; qs[qr][qc+3]=qv.w;
        const float* kp = Kb + (size_t)kr * DM + k0 + kc;
        float4 k0v = *(const float4*)kp;
        float4 k1v = *(const float4*)(kp + 4);
        ks[kr][kc+0]=k0v.x; ks[kr][kc+1]=k0v.y; ks[kr][kc+2]=k0v.z; ks[kr][kc+3]=k0v.w;
        ks[kr][kc+4]=k1v.x; ks[kr][kc+5]=k1v.y; ks[kr][kc+6]=k1v.z; ks[kr][kc+7]=k1v.w;
        __syncthreads();
#pragma unroll
        for (int kk = 0; kk < 16; ++kk) {
            float a[4], bb[8];
#pragma unroll
            for (int i = 0; i < 4; ++i) a[i] = qs[ty*4+i][kk];
#pragma unroll
            for (int j = 0; j < 8; ++j) bb[j] = ks[tx*8+j][kk];
#pragma unroll
            for (int i = 0; i < 4; ++i)
#pragma unroll
                for (int j = 0; j < 8; ++j) acc[i][j] = fmaf(a[i], bb[j], acc[i][j]);
        }
        __syncthreads();
    }
#pragma unroll
    for (int i = 0; i < 4; ++i) {
        size_t row = (size_t)b * LQ + ty*4 + i;
#pragma unroll
        for (int j = 0; j < 8; ++j)
            S[row * LKV + jt*128 + tx*8 + j] = acc[i][j] * SCALE;
    }
}

// ---------------- in-place row softmax over 4096 ----------------------------
__device__ __forceinline__ float wave_red_max(float v) {
#pragma unroll
    for (int off = 32; off > 0; off >>= 1) v = fmaxf(v, __shfl_down(v, off));
    return v;
}
__device__ __forceinline__ float wave_red_sum(float v) {
#pragma unroll
    for (int off = 32; off > 0; off >>= 1) v += __shfl_down(v, off);
    return v;
}

__global__ __launch_bounds__(256) void softmax_kernel(float* __restrict__ S) {
    __shared__ float redm[4], reds[4];
    float* p = S + (size_t)blockIdx.x * LKV;
    const int t = threadIdx.x;

    float vals[16];
    float m = -INFINITY;
#pragma unroll
    for (int i = 0; i < 16; ++i) {
        vals[i] = p[t + 256*i];
        m = fmaxf(m, vals[i]);
    }
    m = wave_red_max(m);
    if ((t & 63) == 0) redm[t >> 6] = m;
    __syncthreads();
    m = fmaxf(fmaxf(redm[0], redm[1]), fmaxf(redm[2], redm[3]));

    float sum = 0.f;
#pragma unroll
    for (int i = 0; i < 16; ++i) {
        vals[i] = __expf(vals[i] - m);
        sum += vals[i];
    }
    sum = wave_red_sum(sum);
    if ((t & 63) == 0) reds[t >> 6] = sum;
    __syncthreads();
    sum = reds[0] + reds[1] + reds[2] + reds[3];
    const float inv = 1.0f / sum;
#pragma unroll
    for (int i = 0; i < 16; ++i) p[t + 256*i] = vals[i] * inv;
}

// ---------------- out: O[b,i,e] = sum_j P[b,i,j] V[b,j,e] -------------------
// grid: (NB, 512/128), block 256, 4x8 microtile, BK=16
__global__ __launch_bounds__(256) void pv_kernel(const float* __restrict__ P,
                                                 const float* __restrict__ V,
                                                 float* __restrict__ O) {
    __shared__ float ps[64][17];
    __shared__ float vs[16][132];
    const int b = blockIdx.x, et = blockIdx.y;
    const int t = threadIdx.x;
    const int tx = t & 15, ty = t >> 4;

    const float* Pb = P + (size_t)b * LQ * LKV;
    const float* Vb = V + (size_t)b * LKV * DM;

    float acc[4][8];
#pragma unroll
    for (int i = 0; i < 4; ++i)
#pragma unroll
        for (int j = 0; j < 8; ++j) acc[i][j] = 0.f;

    const int pr = t >> 2, pc = (t & 3) << 2;   // 64 x 16 of P
    const int vr = t >> 4, vc = (t & 15) << 3;  // 16 x 128 of V

    for (int k0 = 0; k0 < LKV; k0 += 16) {
        float4 pv = *(const float4*)(Pb + (size_t)pr * LKV + k0 + pc);
        ps[pr][pc+0]=pv.x; ps[pr][pc+1]=pv.y; ps[pr][pc+2]=pv.z; ps[pr][pc+3]=pv.w;
        const float* vp = Vb + (size_t)(k0 + vr) * DM + et*128 + vc;
        float4 v0 = *(const float4*)vp;
        float4 v1 = *(const float4*)(vp + 4);
        vs[vr][vc+0]=v0.x; vs[vr][vc+1]=v0.y; vs[vr][vc+2]=v0.z; vs[vr][vc+3]=v0.w;
        vs[vr][vc+4]=v1.x; vs[vr][vc+5]=v1.y; vs[vr][vc+6]=v1.z; vs[vr][vc+7]=v1.w;
        __syncthreads();
#pragma unroll
        for (int kk = 0; kk < 16; ++kk) {
            float a[4], bb[8];
#pragma unroll
            for (int i = 0; i < 4; ++i) a[i] = ps[ty*4+i][kk];
#pragma unroll
            for (int j = 0; j < 8; ++j) bb[j] = vs[kk][tx*8+j];
#pragma unroll
            for (int i = 0; i < 4; ++i)
#pragma unroll
                for (int j = 0; j < 8; ++j) acc[i][j] = fmaf(a[i], bb[j], acc[i][j]);
        }
        __syncthreads();
    }
#pragma unroll
    for (int i = 0; i < 4; ++i) {
        size_t row = (size_t)b * LQ + ty*4 + i;
#pragma unroll
        for (int j = 0; j < 8; ++j)
            O[row * DM + et*128 + tx*8 + j] = acc[i][j];
    }
}

extern "C" void kernel_launch(void* const* d_in, const int* in_sizes, int n_in,
                              void* d_out, int out_size, void* d_ws, size_t ws_size,
                              hipStream_t stream) {
    const float* x1 = (const float*)d_in[0];   // [32,64,512]
    const float* x2 = (const float*)d_in[1];   // [32,4096,512]
    // d_in[2] = mask, unused by the reference forward
    const float* wq = (const float*)d_in[3];
    const float* bq = (const float*)d_in[4];
    const float* wk = (const float*)d_in[5];
    const float* bk = (const float*)d_in[6];
    const float* wv = (const float*)d_in[7];
    const float* bv = (const float*)d_in[8];
    float* out = (float*)d_out;

    // workspace layout (floats): q | k | v | s   — needs ~548 MiB
    float* q = (float*)d_ws;
    float* k = q + (size_t)NB * LQ * DM;          // +1,048,576
    float* v = k + (size_t)NB * LKV * DM;         // +67,108,864
    float* s = v + (size_t)NB * LKV * DM;         // +67,108,864 (s: 8,388,608)

    // projections
    linear_bt<<<dim3((NB*LQ)/128, DM/128), 256, 0, stream>>>(x1, wq, bq, q);
    linear_bt<<<dim3((NB*LKV)/128, DM/128), 256, 0, stream>>>(x2, wk, bk, k);
    linear_bt<<<dim3((NB*LKV)/128, DM/128), 256, 0, stream>>>(x2, wv, bv, v);
    // attention
    qk_kernel<<<dim3(NB, LKV/128), 256, 0, stream>>>(q, k, s);
    softmax_kernel<<<NB*LQ, 256, 0, stream>>>(s);
    pv_kernel<<<dim3(NB, DM/128), 256, 0, stream>>>(s, v, out);
}

// Round 2
// 1063.892 us; speedup vs baseline: 3.4971x; 3.4971x over previous
//
#include <hip/hip_runtime.h>
#include <math.h>

// Cross-attention forward, B=32, LQ=64, LKV=4096, D=512, fp32 in/out.
// Round 2: bf16 MFMA with hi/lo split precision.
//   K/Q proj: 3-term split GEMM (xhi*whi + xlo*whi + xhi*wlo), epilogue re-splits
//             the fp32 result into (hi|lo) bf16 pairs for the QK GEMM.
//   V proj:   2-term split (x-side), epilogue writes v TRANSPOSED (bf16) via LDS
//             so PV is a K-major gemm_bt.
//   QK:       3-term split on (q2,k2), *sqrt(512), fp32 scores.
//   softmax:  fp32 in, bf16 probs out.
//   PV:       plain bf16 MFMA (post-softmax errors don't amplify).
// Workspace ~460 MB (round 0 proved >=548 MB available).

#define LQ 64
#define LKV 4096
#define NB 32
#define DM 512
#define SCALE 22.627416997969522f   // sqrt(512); reference multiplies scores by this

typedef __attribute__((ext_vector_type(8))) short bf16x8;     // MFMA A/B frag (4 VGPR)
typedef __attribute__((ext_vector_type(4))) float f32x4;      // MFMA C/D frag
typedef __attribute__((ext_vector_type(8))) unsigned short u16x8;
typedef __attribute__((ext_vector_type(4))) unsigned short u16x4;

__device__ __forceinline__ unsigned short f2bf(float f) {   // RNE fp32->bf16
    unsigned u = __float_as_uint(f);
    u += 0x7fffu + ((u >> 16) & 1u);
    return (unsigned short)(u >> 16);
}
__device__ __forceinline__ float bf2f(unsigned short s) {
    return __uint_as_float(((unsigned)s) << 16);
}

// async global->LDS, 16B per lane; LDS dest = wave-uniform base + lane*16
__device__ __forceinline__ void gld16(const void* g, void* l) {
    __builtin_amdgcn_global_load_lds(
        (const __attribute__((address_space(1))) unsigned int*)g,
        (__attribute__((address_space(3))) unsigned int*)l, 16, 0, 0);
}

// ---------------- weight split: w fp32 [512*512] -> hi, lo bf16 -------------
__global__ void conv_w_kernel(const float* __restrict__ w,
                              unsigned short* __restrict__ hi,
                              unsigned short* __restrict__ lo) {
    int idx = (blockIdx.x * 256 + threadIdx.x) * 4;
    float4 v = *(const float4*)(w + idx);
    u16x4 h, l;
    h[0]=f2bf(v.x); h[1]=f2bf(v.y); h[2]=f2bf(v.z); h[3]=f2bf(v.w);
    l[0]=f2bf(v.x-bf2f(h[0])); l[1]=f2bf(v.y-bf2f(h[1]));
    l[2]=f2bf(v.z-bf2f(h[2])); l[3]=f2bf(v.w-bf2f(h[3]));
    *(u16x4*)(hi + idx) = h;
    *(u16x4*)(lo + idx) = l;
}

// ---------------- projection GEMM: Y[M,512] = X[M,512] @ W^T + b ------------
// BM=BN=128, BK=32, 256 thr (4 waves, 2x2), 16x16x32 bf16 MFMA, 4x4 tiles/wave.
// A (fp32 X) converted in-kernel to hi/lo bf16 in padded LDS; B (pre-split
// weights) staged raw via global_load_lds.
// NTERMS: 3 = xhi*whi + xlo*whi + xhi*wlo (Q/K), 2 = xhi*whi + xlo*whi (V)
// EPI: 0 = write (hi|lo) bf16 pair [row*1024 + c] / [+512+c]  (q2/k2)
//      1 = write bf16 transposed v_t[col*ldOut + row] via LDS transpose
template<int NTERMS, int EPI>
__global__ void proj_kernel(const float* __restrict__ X,
                            const unsigned short* __restrict__ Bhi,
                            const unsigned short* __restrict__ Blo,
                            const float* __restrict__ bias,
                            unsigned short* __restrict__ out,
                            int ldOut) {
    __shared__ unsigned short smem[18432];          // 36 KB
    unsigned short* Ah = smem;                      // [128][40] padded (10 KB)
    unsigned short* Al = smem + 5120;               // [128][40]
    unsigned short* Bh = smem + 10240;              // [128][32] (8 KB)
    unsigned short* Bl = smem + 14336;              // [128][32]

    const int bm = blockIdx.x, bn = blockIdx.y;
    const int t = threadIdx.x, w = t >> 6, l = t & 63;
    const int wm = (w >> 1) * 64, wn = (w & 1) * 64;
    const int c16 = l & 15, q8 = (l >> 4) << 3, q = l >> 4;

    f32x4 acc[4][4];
#pragma unroll
    for (int i = 0; i < 4; ++i)
#pragma unroll
        for (int j = 0; j < 4; ++j) acc[i][j] = (f32x4){0.f,0.f,0.f,0.f};

    const int rowA = w * 32 + (l >> 1);          // 0..127
    const int colh = (l & 1) << 4;               // 0 or 16
    const float* xp = X + (size_t)(bm * 128 + rowA) * DM + colh;
    const int rB = l >> 2, cB = (l & 3) << 3;

    for (int k0 = 0; k0 < DM; k0 += 32) {
        // ---- A: fp32 -> hi/lo bf16 -> padded LDS
        float ff[16];
        *(float4*)&ff[0]  = *(const float4*)(xp + k0);
        *(float4*)&ff[4]  = *(const float4*)(xp + k0 + 4);
        *(float4*)&ff[8]  = *(const float4*)(xp + k0 + 8);
        *(float4*)&ff[12] = *(const float4*)(xp + k0 + 12);
        u16x8 vh0, vh1, vl0, vl1;
#pragma unroll
        for (int i = 0; i < 8; ++i) {
            unsigned short h = f2bf(ff[i]);
            vh0[i] = h; vl0[i] = f2bf(ff[i] - bf2f(h));
            unsigned short h2 = f2bf(ff[8+i]);
            vh1[i] = h2; vl1[i] = f2bf(ff[8+i] - bf2f(h2));
        }
        *(u16x8*)&Ah[rowA*40 + colh]     = vh0;
        *(u16x8*)&Ah[rowA*40 + colh + 8] = vh1;
        *(u16x8*)&Al[rowA*40 + colh]     = vl0;
        *(u16x8*)&Al[rowA*40 + colh + 8] = vl1;
        // ---- B: raw bf16 via global_load_lds
#pragma unroll
        for (int j = 0; j < 2; ++j) {
            int r = bn * 128 + w * 32 + j * 16 + rB;
            gld16(Bhi + (size_t)r * DM + k0 + cB, &Bh[(w*32 + j*16) * 32]);
            if (NTERMS == 3)
                gld16(Blo + (size_t)r * DM + k0 + cB, &Bl[(w*32 + j*16) * 32]);
        }
        __syncthreads();
        bf16x8 ah[4], al[4], bh[4], bl[4];
#pragma unroll
        for (int mt = 0; mt < 4; ++mt) {
            ah[mt] = *(const bf16x8*)&Ah[(wm + mt*16 + c16) * 40 + q8];
            al[mt] = *(const bf16x8*)&Al[(wm + mt*16 + c16) * 40 + q8];
        }
#pragma unroll
        for (int nt = 0; nt < 4; ++nt) {
            bh[nt] = *(const bf16x8*)&Bh[(wn + nt*16 + c16) * 32 + q8];
            if (NTERMS == 3)
                bl[nt] = *(const bf16x8*)&Bl[(wn + nt*16 + c16) * 32 + q8];
        }
#pragma unroll
        for (int nt = 0; nt < 4; ++nt)
#pragma unroll
            for (int mt = 0; mt < 4; ++mt) {
                acc[mt][nt] = __builtin_amdgcn_mfma_f32_16x16x32_bf16(ah[mt], bh[nt], acc[mt][nt], 0, 0, 0);
                acc[mt][nt] = __builtin_amdgcn_mfma_f32_16x16x32_bf16(al[mt], bh[nt], acc[mt][nt], 0, 0, 0);
                if (NTERMS == 3)
                    acc[mt][nt] = __builtin_amdgcn_mfma_f32_16x16x32_bf16(ah[mt], bl[nt], acc[mt][nt], 0, 0, 0);
            }
        __syncthreads();
    }

    if (EPI == 0) {
        // C/D layout: row = q*4+reg, col = lane&15
#pragma unroll
        for (int mt = 0; mt < 4; ++mt)
#pragma unroll
            for (int nt = 0; nt < 4; ++nt) {
                int col = bn * 128 + wn + nt * 16 + c16;
                float b = bias[col];
#pragma unroll
                for (int r = 0; r < 4; ++r) {
                    size_t row = (size_t)bm * 128 + wm + mt * 16 + q * 4 + r;
                    float y = acc[mt][nt][r] + b;
                    unsigned short hi = f2bf(y);
                    out[row * 1024 + col]       = hi;
                    out[row * 1024 + 512 + col] = f2bf(y - bf2f(hi));
                }
            }
    } else {
        // transpose via LDS: T[128][128] bf16, then coalesced global stores
        unsigned short* T = smem;   // 16384 ushorts = 32 KB
#pragma unroll
        for (int mt = 0; mt < 4; ++mt)
#pragma unroll
            for (int nt = 0; nt < 4; ++nt) {
                int nl = wn + nt * 16 + c16;
                int ml = wm + mt * 16 + q * 4;
                float b = bias[bn * 128 + nl];
                u16x4 pk;
#pragma unroll
                for (int r = 0; r < 4; ++r) pk[r] = f2bf(acc[mt][nt][r] + b);
                *(u16x4*)&T[nl * 128 + ml] = pk;
            }
        __syncthreads();
        int n = t >> 1, seg = (t & 1) * 64;
        size_t gb = (size_t)(bn * 128 + n) * (size_t)ldOut + (size_t)bm * 128 + seg;
#pragma unroll
        for (int i = 0; i < 8; ++i)
            *(u16x8*)(out + gb + i * 8) = *(const u16x8*)&T[n * 128 + seg + i * 8];
    }
}

// ---------------- QK: S[b,i,j] = sqrt(512) * (q.k), 3-term split ------------
// BM=64, BN=128, BK=32, per-k0 staging of qhi/qlo/khi/klo; wave = 64x32 (4x2)
__global__ void qk_kernel(const unsigned short* __restrict__ Q2,
                          const unsigned short* __restrict__ K2,
                          float* __restrict__ S) {
    __shared__ unsigned short Ahh[64*32], All_[64*32], Bhh[128*32], Bll[128*32];
    const int b = blockIdx.x, bn = blockIdx.y;
    const int t = threadIdx.x, w = t >> 6, l = t & 63;
    const int wn = w * 32;
    const int c16 = l & 15, q8 = (l >> 4) << 3, q = l >> 4;
    const int rB = l >> 2, cB = (l & 3) << 3;

    f32x4 acc[4][2];
#pragma unroll
    for (int i = 0; i < 4; ++i)
#pragma unroll
        for (int j = 0; j < 2; ++j) acc[i][j] = (f32x4){0.f,0.f,0.f,0.f};

    for (int k0 = 0; k0 < 512; k0 += 32) {
        {
            int r = w * 16 + rB;
            size_t base = ((size_t)b * 64 + r) * 1024 + k0 + cB;
            gld16(Q2 + base,       &Ahh[(w*16) * 32]);
            gld16(Q2 + base + 512, &All_[(w*16) * 32]);
        }
#pragma unroll
        for (int j = 0; j < 2; ++j) {
            int r = bn * 128 + w * 32 + j * 16 + rB;
            size_t base = ((size_t)b * 4096 + r) * 1024 + k0 + cB;
            gld16(K2 + base,       &Bhh[(w*32 + j*16) * 32]);
            gld16(K2 + base + 512, &Bll[(w*32 + j*16) * 32]);
        }
        __syncthreads();
        bf16x8 ah[4], al[4], bh[2], bl[2];
#pragma unroll
        for (int mt = 0; mt < 4; ++mt) {
            ah[mt] = *(const bf16x8*)&Ahh[(mt*16 + c16) * 32 + q8];
            al[mt] = *(const bf16x8*)&All_[(mt*16 + c16) * 32 + q8];
        }
#pragma unroll
        for (int nt = 0; nt < 2; ++nt) {
            bh[nt] = *(const bf16x8*)&Bhh[(wn + nt*16 + c16) * 32 + q8];
            bl[nt] = *(const bf16x8*)&Bll[(wn + nt*16 + c16) * 32 + q8];
        }
#pragma unroll
        for (int nt = 0; nt < 2; ++nt)
#pragma unroll
            for (int mt = 0; mt < 4; ++mt) {
                acc[mt][nt] = __builtin_amdgcn_mfma_f32_16x16x32_bf16(ah[mt], bh[nt], acc[mt][nt], 0, 0, 0);
                acc[mt][nt] = __builtin_amdgcn_mfma_f32_16x16x32_bf16(al[mt], bh[nt], acc[mt][nt], 0, 0, 0);
                acc[mt][nt] = __builtin_amdgcn_mfma_f32_16x16x32_bf16(ah[mt], bl[nt], acc[mt][nt], 0, 0, 0);
            }
        __syncthreads();
    }
#pragma unroll
    for (int mt = 0; mt < 4; ++mt)
#pragma unroll
        for (int nt = 0; nt < 2; ++nt)
#pragma unroll
            for (int r = 0; r < 4; ++r) {
                int row = mt * 16 + q * 4 + r;
                int col = bn * 128 + wn + nt * 16 + c16;
                S[((size_t)b * 64 + row) * 4096 + col] = acc[mt][nt][r] * SCALE;
            }
}

// ---------------- softmax: fp32 scores -> bf16 probs ------------------------
__global__ void softmax_kernel(const float* __restrict__ S,
                               unsigned short* __restrict__ P) {
    __shared__ float redm[4], reds[4];
    const size_t base = (size_t)blockIdx.x * 4096;
    const int t = threadIdx.x;
    float v[16];
    float m = -1e30f;
#pragma unroll
    for (int i = 0; i < 16; ++i) {
        v[i] = S[base + t + 256 * i];
        m = fmaxf(m, v[i]);
    }
#pragma unroll
    for (int off = 32; off > 0; off >>= 1) m = fmaxf(m, __shfl_down(m, off));
    if ((t & 63) == 0) redm[t >> 6] = m;
    __syncthreads();
    m = fmaxf(fmaxf(redm[0], redm[1]), fmaxf(redm[2], redm[3]));
    float s = 0.f;
#pragma unroll
    for (int i = 0; i < 16; ++i) { v[i] = __expf(v[i] - m); s += v[i]; }
#pragma unroll
    for (int off = 32; off > 0; off >>= 1) s += __shfl_down(s, off);
    if ((t & 63) == 0) reds[t >> 6] = s;
    __syncthreads();
    s = reds[0] + reds[1] + reds[2] + reds[3];
    const float inv = 1.0f / s;
#pragma unroll
    for (int i = 0; i < 16; ++i) P[base + t + 256 * i] = f2bf(v[i] * inv);
}

// ---------------- PV: O[b,i,e] = sum_j P[b,i,j] v_t[e, b*4096+j] ------------
// BM=64, BN=64, BK=32, plain bf16; wave = 64x16 (4x1)
__global__ void pv_kernel(const unsigned short* __restrict__ P,
                          const unsigned short* __restrict__ Vt,
                          float* __restrict__ O) {
    __shared__ unsigned short As_[64*32], Bs_[64*32];
    const int b = blockIdx.x, bn = blockIdx.y;
    const int t = threadIdx.x, w = t >> 6, l = t & 63;
    const int wn = w * 16;
    const int c16 = l & 15, q8 = (l >> 4) << 3, q = l >> 4;
    const int rB = l >> 2, cB = (l & 3) << 3;

    f32x4 acc[4];
#pragma unroll
    for (int i = 0; i < 4; ++i) acc[i] = (f32x4){0.f,0.f,0.f,0.f};

    for (int k0 = 0; k0 < 4096; k0 += 32) {
        {
            int r = w * 16 + rB;
            gld16(P + ((size_t)b * 64 + r) * 4096 + k0 + cB, &As_[(w*16) * 32]);
            int rb = bn * 64 + r;
            gld16(Vt + (size_t)rb * ((size_t)NB * LKV) + (size_t)b * 4096 + k0 + cB,
                  &Bs_[(w*16) * 32]);
        }
        __syncthreads();
        bf16x8 a_[4], b_;
#pragma unroll
        for (int mt = 0; mt < 4; ++mt)
            a_[mt] = *(const bf16x8*)&As_[(mt*16 + c16) * 32 + q8];
        b_ = *(const bf16x8*)&Bs_[(wn + c16) * 32 + q8];
#pragma unroll
        for (int mt = 0; mt < 4; ++mt)
            acc[mt] = __builtin_amdgcn_mfma_f32_16x16x32_bf16(a_[mt], b_, acc[mt], 0, 0, 0);
        __syncthreads();
    }
#pragma unroll
    for (int mt = 0; mt < 4; ++mt)
#pragma unroll
        for (int r = 0; r < 4; ++r)
            O[((size_t)b * 64 + mt * 16 + q * 4 + r) * 512 + bn * 64 + wn + c16] = acc[mt][r];
}

extern "C" void kernel_launch(void* const* d_in, const int* in_sizes, int n_in,
                              void* d_out, int out_size, void* d_ws, size_t ws_size,
                              hipStream_t stream) {
    const float* x1 = (const float*)d_in[0];   // [32,64,512]
    const float* x2 = (const float*)d_in[1];   // [32,4096,512]
    const float* wq = (const float*)d_in[3];
    const float* bq = (const float*)d_in[4];
    const float* wk = (const float*)d_in[5];
    const float* bk = (const float*)d_in[6];
    const float* wv = (const float*)d_in[7];
    const float* bv = (const float*)d_in[8];
    float* out = (float*)d_out;

    // workspace layout (~460 MB)
    char* ws = (char*)d_ws;
    unsigned short* k2  = (unsigned short*)(ws);                 // [131072][1024] bf16 hi|lo
    unsigned short* v_t = (unsigned short*)(ws + 268435456);     // [512][131072] bf16
    float*          s   = (float*)(ws + 402653184);              // [2048][4096] fp32
    unsigned short* p   = (unsigned short*)(ws + 436207616);     // [2048][4096] bf16
    unsigned short* q2  = (unsigned short*)(ws + 452984832);     // [2048][1024]
    unsigned short* wqh = (unsigned short*)(ws + 457179136);
    unsigned short* wql = wqh + 262144;
    unsigned short* wkh = wql + 262144;
    unsigned short* wkl = wkh + 262144;
    unsigned short* wvh = wkl + 262144;
    unsigned short* wvl = wvh + 262144;   // unused (2-term V), kept for symmetry

    conv_w_kernel<<<256, 256, 0, stream>>>(wq, wqh, wql);
    conv_w_kernel<<<256, 256, 0, stream>>>(wk, wkh, wkl);
    conv_w_kernel<<<256, 256, 0, stream>>>(wv, wvh, wvl);

    proj_kernel<3,0><<<dim3(16, 4),   256, 0, stream>>>(x1, wqh, wql, bq, q2, 0);
    proj_kernel<3,0><<<dim3(1024, 4), 256, 0, stream>>>(x2, wkh, wkl, bk, k2, 0);
    proj_kernel<2,1><<<dim3(1024, 4), 256, 0, stream>>>(x2, wvh, wvl, bv, v_t, NB * LKV);

    qk_kernel<<<dim3(NB, 32), 256, 0, stream>>>(q2, k2, s);
    softmax_kernel<<<NB * LQ, 256, 0, stream>>>(s, p);
    pv_kernel<<<dim3(NB, 8), 256, 0, stream>>>(p, v_t, out);
}

// Round 3
// 1042.726 us; speedup vs baseline: 3.5680x; 1.0203x over previous
//
#include <hip/hip_runtime.h>
#include <math.h>

// Cross-attention forward, B=32, LQ=64, LKV=4096, D=512, fp32 in/out.
// Round 3 pipeline:
//   split:   fp32 -> (hi,lo) bf16 pair, RNE. Run on wq,wk,wv,x1,x2(half).
//   proj:    pure-bf16 MFMA GEMM (m97-style, gld16 all tiles). Merged K+V:
//            grid(bn=8 fast, bm) so 8 blocks share the A-tile via L2.
//            bn<4: 3-term K -> k2 hi|lo.  bn>=4: 2-term V -> v_t transposed.
//   attn:    per (batch, 512-key chunk): QK 3-term (S in regs), one softmax,
//            P->LDS, PV; writes unnormalized partial O + (m,l).
//   combine: merge 8 chunk-partials per row.
// Workspace 548.4 MB (<= 573.5 MB proven in round 0).

#define LQ 64
#define LKV 4096
#define NB 32
#define DM 512
#define SCALE 22.627416997969522f   // sqrt(512)
#define KEYS_TOTAL (NB * LKV)       // 131072
#define HALF_KEYS 65536
#define NCHUNK 8                    // chunks per batch
#define CHUNK 512                   // keys per attn block

typedef __attribute__((ext_vector_type(8))) short bf16x8;
typedef __attribute__((ext_vector_type(4))) float f32x4;
typedef __attribute__((ext_vector_type(8))) unsigned short u16x8;
typedef __attribute__((ext_vector_type(4))) unsigned short u16x4;

__device__ __forceinline__ unsigned short f2bf(float f) {   // RNE fp32->bf16
    unsigned u = __float_as_uint(f);
    u += 0x7fffu + ((u >> 16) & 1u);
    return (unsigned short)(u >> 16);
}
__device__ __forceinline__ float bf2f(unsigned short s) {
    return __uint_as_float(((unsigned)s) << 16);
}
__device__ __forceinline__ void gld16(const void* g, void* l) {
    __builtin_amdgcn_global_load_lds(
        (const __attribute__((address_space(1))) unsigned int*)g,
        (__attribute__((address_space(3))) unsigned int*)l, 16, 0, 0);
}

// ---------------- split: fp32 -> hi/lo bf16 ---------------------------------
__global__ __launch_bounds__(256) void split_kernel(const float* __restrict__ src,
                                                    unsigned short* __restrict__ hi,
                                                    unsigned short* __restrict__ lo) {
    int idx = (blockIdx.x * 256 + threadIdx.x) * 4;
    float4 v = *(const float4*)(src + idx);
    u16x4 h, l;
    h[0]=f2bf(v.x); h[1]=f2bf(v.y); h[2]=f2bf(v.z); h[3]=f2bf(v.w);
    l[0]=f2bf(v.x-bf2f(h[0])); l[1]=f2bf(v.y-bf2f(h[1]));
    l[2]=f2bf(v.z-bf2f(h[2])); l[3]=f2bf(v.w-bf2f(h[3]));
    *(u16x4*)(hi + idx) = h;
    *(u16x4*)(lo + idx) = l;
}

// ---------------- merged projection GEMM ------------------------------------
// BM=BN=128, BK=32, 256 thr (4 waves 2x2), 16x16x32 bf16.
// bn<4: K-path 3-term -> outK[row*1024 + col] hi, [+512] lo (row = key0+local)
// bn>=4: V-path 2-term -> outV[(dim)*KEYS_TOTAL + key] bf16, via LDS transpose
__global__ __launch_bounds__(256) void proj_kernel(
        const unsigned short* __restrict__ Xh, const unsigned short* __restrict__ Xl,
        const unsigned short* __restrict__ WKh, const unsigned short* __restrict__ WKl,
        const float* __restrict__ biasK, unsigned short* __restrict__ outK,
        const unsigned short* __restrict__ WVh,
        const float* __restrict__ biasV, unsigned short* __restrict__ outV,
        int key0) {
    __shared__ unsigned short smem[16384];          // 32 KB
    unsigned short* Ah = smem;                      // [128][32]
    unsigned short* Al = smem + 4096;
    unsigned short* Bh = smem + 8192;
    unsigned short* Bl = smem + 12288;

    const int bn = blockIdx.x, bm = blockIdx.y;
    const bool kpath = (bn < 4);
    const int bncol = kpath ? bn : (bn - 4);
    const unsigned short* Wh = kpath ? WKh : WVh;

    const int t = threadIdx.x, w = t >> 6, l = t & 63;
    const int wm = (w >> 1) * 64, wn = (w & 1) * 64;
    const int c16 = l & 15, q = l >> 4, q8 = q << 3;
    const int rB = l >> 2, cB = (l & 3) << 3;

    f32x4 acc[4][4];
#pragma unroll
    for (int i = 0; i < 4; ++i)
#pragma unroll
        for (int j = 0; j < 4; ++j) acc[i][j] = (f32x4){0.f,0.f,0.f,0.f};

    for (int k0 = 0; k0 < DM; k0 += 32) {
#pragma unroll
        for (int j = 0; j < 2; ++j) {
            int r = w * 32 + j * 16;                        // tile row base
            size_t ga = (size_t)(bm * 128 + r + rB) * DM + k0 + cB;
            gld16(Xh + ga, &Ah[r * 32]);
            gld16(Xl + ga, &Al[r * 32]);
            size_t gb = (size_t)(bncol * 128 + r + rB) * DM + k0 + cB;
            gld16(Wh + gb, &Bh[r * 32]);
            if (kpath) gld16(WKl + gb, &Bl[r * 32]);
        }
        __syncthreads();
        bf16x8 ah[4], al[4];
#pragma unroll
        for (int mt = 0; mt < 4; ++mt) {
            ah[mt] = *(const bf16x8*)&Ah[(wm + mt*16 + c16) * 32 + q8];
            al[mt] = *(const bf16x8*)&Al[(wm + mt*16 + c16) * 32 + q8];
        }
#pragma unroll
        for (int nt = 0; nt < 4; ++nt) {
            bf16x8 bh = *(const bf16x8*)&Bh[(wn + nt*16 + c16) * 32 + q8];
#pragma unroll
            for (int mt = 0; mt < 4; ++mt) {
                acc[mt][nt] = __builtin_amdgcn_mfma_f32_16x16x32_bf16(ah[mt], bh, acc[mt][nt], 0, 0, 0);
                acc[mt][nt] = __builtin_amdgcn_mfma_f32_16x16x32_bf16(al[mt], bh, acc[mt][nt], 0, 0, 0);
            }
            if (kpath) {
                bf16x8 bl = *(const bf16x8*)&Bl[(wn + nt*16 + c16) * 32 + q8];
#pragma unroll
                for (int mt = 0; mt < 4; ++mt)
                    acc[mt][nt] = __builtin_amdgcn_mfma_f32_16x16x32_bf16(ah[mt], bl, acc[mt][nt], 0, 0, 0);
            }
        }
        __syncthreads();
    }

    if (kpath) {
#pragma unroll
        for (int mt = 0; mt < 4; ++mt)
#pragma unroll
            for (int nt = 0; nt < 4; ++nt) {
                int col = bncol * 128 + wn + nt * 16 + c16;
                float bia = biasK[col];
#pragma unroll
                for (int r = 0; r < 4; ++r) {
                    size_t row = (size_t)key0 + bm * 128 + wm + mt * 16 + q * 4 + r;
                    float y = acc[mt][nt][r] + bia;
                    unsigned short hi = f2bf(y);
                    outK[row * 1024 + col]       = hi;
                    outK[row * 1024 + 512 + col] = f2bf(y - bf2f(hi));
                }
            }
    } else {
        unsigned short* T = smem;     // [128][128] bf16 = 32 KB
#pragma unroll
        for (int mt = 0; mt < 4; ++mt)
#pragma unroll
            for (int nt = 0; nt < 4; ++nt) {
                int nl = wn + nt * 16 + c16;                // dim (local)
                int ml = wm + mt * 16 + q * 4;              // key (local)
                float bia = biasV[bncol * 128 + nl];
                u16x4 pk;
#pragma unroll
                for (int r = 0; r < 4; ++r) pk[r] = f2bf(acc[mt][nt][r] + bia);
                *(u16x4*)&T[nl * 128 + ml] = pk;
            }
        __syncthreads();
        int n = t >> 1, seg = (t & 1) * 64;
        size_t gb = (size_t)(bncol * 128 + n) * KEYS_TOTAL + (size_t)key0 + bm * 128 + seg;
#pragma unroll
        for (int i = 0; i < 8; ++i)
            *(u16x8*)(outV + gb + i * 8) = *(const u16x8*)&T[n * 128 + seg + i * 8];
    }
}

// ---------------- fused attention: per (chunk, batch) -----------------------
// 512 thr = 8 waves. Wave w: QK keys [w*64,+64), PV dims [w*64,+64).
// S[64x512] in registers (acc reused as O after softmax).
__global__ __launch_bounds__(512, 2) void attn_kernel(
        const unsigned short* __restrict__ Q2,    // [2048][1024] hi|lo
        const unsigned short* __restrict__ K2,    // [131072][1024] hi|lo
        const unsigned short* __restrict__ Vt,    // [512][131072]
        float* __restrict__ Opart,                // [256][64][512]
        float* __restrict__ ML) {                 // [256][128] (m|l)
    __shared__ char smem_raw[102400];
    unsigned short* Qh = (unsigned short*)smem_raw;            // [64][32]
    unsigned short* Ql = (unsigned short*)(smem_raw + 4096);
    unsigned short* Kh = (unsigned short*)(smem_raw + 8192);   // [512][32]
    unsigned short* Kl = (unsigned short*)(smem_raw + 40960);  // ..73728
    unsigned short* Pb = (unsigned short*)smem_raw;            // [64][520] ..66560
    unsigned short* Vb = (unsigned short*)(smem_raw + 66560);  // [512][32] ..99328
    float* redb = (float*)(smem_raw + 99328);                  // [8][64]
    float* mrow = (float*)(smem_raw + 101376);                 // [64]
    float* lrow = (float*)(smem_raw + 101632);                 // [64]

    const int c = blockIdx.x, b = blockIdx.y;
    const int t = threadIdx.x, w = t >> 6, l = t & 63;
    const int c16 = l & 15, q = l >> 4, q8 = q << 3;
    const int rB = l >> 2, cB = (l & 3) << 3;
    const size_t key0 = (size_t)b * LKV + (size_t)c * CHUNK;

    f32x4 acc[4][4];
#pragma unroll
    for (int i = 0; i < 4; ++i)
#pragma unroll
        for (int j = 0; j < 4; ++j) acc[i][j] = (f32x4){0.f,0.f,0.f,0.f};

    // ---- QK: S[64 rows][512 keys], wave w owns keys w*64..w*64+63
    for (int k0 = 0; k0 < DM; k0 += 32) {
        if (w < 4)
            gld16(Q2 + (size_t)(b * 64 + w * 16 + rB) * 1024 + k0 + cB, &Qh[(w * 16) * 32]);
        else
            gld16(Q2 + (size_t)(b * 64 + (w - 4) * 16 + rB) * 1024 + 512 + k0 + cB, &Ql[((w - 4) * 16) * 32]);
#pragma unroll
        for (int j = 0; j < 4; ++j) {
            int r = j * 128 + w * 16;
            size_t krow = key0 + r + rB;
            gld16(K2 + krow * 1024 + k0 + cB,       &Kh[r * 32]);
            gld16(K2 + krow * 1024 + 512 + k0 + cB, &Kl[r * 32]);
        }
        __syncthreads();
        bf16x8 ah[4], al[4];
#pragma unroll
        for (int mt = 0; mt < 4; ++mt) {
            ah[mt] = *(const bf16x8*)&Qh[(mt * 16 + c16) * 32 + q8];
            al[mt] = *(const bf16x8*)&Ql[(mt * 16 + c16) * 32 + q8];
        }
#pragma unroll
        for (int nt = 0; nt < 4; ++nt) {
            bf16x8 bh = *(const bf16x8*)&Kh[(w * 64 + nt * 16 + c16) * 32 + q8];
            bf16x8 bl = *(const bf16x8*)&Kl[(w * 64 + nt * 16 + c16) * 32 + q8];
#pragma unroll
            for (int mt = 0; mt < 4; ++mt) {
                acc[mt][nt] = __builtin_amdgcn_mfma_f32_16x16x32_bf16(ah[mt], bh, acc[mt][nt], 0, 0, 0);
                acc[mt][nt] = __builtin_amdgcn_mfma_f32_16x16x32_bf16(al[mt], bh, acc[mt][nt], 0, 0, 0);
                acc[mt][nt] = __builtin_amdgcn_mfma_f32_16x16x32_bf16(ah[mt], bl, acc[mt][nt], 0, 0, 0);
            }
        }
        __syncthreads();
    }

    // ---- softmax over the chunk (rows global over 8 waves' key ranges)
#pragma unroll
    for (int mt = 0; mt < 4; ++mt)
#pragma unroll
        for (int nt = 0; nt < 4; ++nt)
#pragma unroll
            for (int r = 0; r < 4; ++r) acc[mt][nt][r] *= SCALE;

    float rmax_[4][4];
#pragma unroll
    for (int mt = 0; mt < 4; ++mt)
#pragma unroll
        for (int r = 0; r < 4; ++r) {
            float m = acc[mt][0][r];
#pragma unroll
            for (int nt = 1; nt < 4; ++nt) m = fmaxf(m, acc[mt][nt][r]);
            rmax_[mt][r] = m;
        }
#pragma unroll
    for (int off = 1; off < 16; off <<= 1)
#pragma unroll
        for (int mt = 0; mt < 4; ++mt)
#pragma unroll
            for (int r = 0; r < 4; ++r)
                rmax_[mt][r] = fmaxf(rmax_[mt][r], __shfl_xor(rmax_[mt][r], off));
    if (c16 == 0) {
#pragma unroll
        for (int mt = 0; mt < 4; ++mt)
#pragma unroll
            for (int r = 0; r < 4; ++r) redb[w * 64 + mt * 16 + q * 4 + r] = rmax_[mt][r];
    }
    __syncthreads();
    if (t < 64) {
        float m = redb[t];
#pragma unroll
        for (int ww = 1; ww < 8; ++ww) m = fmaxf(m, redb[ww * 64 + t]);
        mrow[t] = m;
    }
    __syncthreads();

    float rsum_[4][4];
#pragma unroll
    for (int mt = 0; mt < 4; ++mt)
#pragma unroll
        for (int r = 0; r < 4; ++r) {
            float m = mrow[mt * 16 + q * 4 + r];
            float s = 0.f;
#pragma unroll
            for (int nt = 0; nt < 4; ++nt) {
                float e = __expf(acc[mt][nt][r] - m);
                acc[mt][nt][r] = e;
                s += e;
            }
            rsum_[mt][r] = s;
        }
#pragma unroll
    for (int off = 1; off < 16; off <<= 1)
#pragma unroll
        for (int mt = 0; mt < 4; ++mt)
#pragma unroll
            for (int r = 0; r < 4; ++r) rsum_[mt][r] += __shfl_xor(rsum_[mt][r], off);
    if (c16 == 0) {
#pragma unroll
        for (int mt = 0; mt < 4; ++mt)
#pragma unroll
            for (int r = 0; r < 4; ++r) redb[w * 64 + mt * 16 + q * 4 + r] = rsum_[mt][r];
    }
    __syncthreads();
    if (t < 64) {
        float s = redb[t];
#pragma unroll
        for (int ww = 1; ww < 8; ++ww) s += redb[ww * 64 + t];
        lrow[t] = s;
    }
    // P -> LDS (bf16, A-operand row-major [row][key], pad 520)
#pragma unroll
    for (int mt = 0; mt < 4; ++mt)
#pragma unroll
        for (int nt = 0; nt < 4; ++nt)
#pragma unroll
            for (int r = 0; r < 4; ++r)
                Pb[(mt * 16 + q * 4 + r) * 520 + w * 64 + nt * 16 + c16] = f2bf(acc[mt][nt][r]);
    __syncthreads();

    // ---- PV: O[64][512], wave w owns dims w*64..w*64+63; reuse acc as O
#pragma unroll
    for (int i = 0; i < 4; ++i)
#pragma unroll
        for (int j = 0; j < 4; ++j) acc[i][j] = (f32x4){0.f,0.f,0.f,0.f};

    for (int ks = 0; ks < CHUNK; ks += 32) {
#pragma unroll
        for (int j = 0; j < 4; ++j) {
            int d = j * 128 + w * 16;
            gld16(Vt + (size_t)(d + rB) * KEYS_TOTAL + key0 + ks + cB, &Vb[d * 32]);
        }
        __syncthreads();
        bf16x8 ap[4];
#pragma unroll
        for (int mt = 0; mt < 4; ++mt)
            ap[mt] = *(const bf16x8*)&Pb[(mt * 16 + c16) * 520 + ks + q8];
#pragma unroll
        for (int nt = 0; nt < 4; ++nt) {
            bf16x8 bv = *(const bf16x8*)&Vb[(w * 64 + nt * 16 + c16) * 32 + q8];
#pragma unroll
            for (int mt = 0; mt < 4; ++mt)
                acc[mt][nt] = __builtin_amdgcn_mfma_f32_16x16x32_bf16(ap[mt], bv, acc[mt][nt], 0, 0, 0);
        }
        __syncthreads();
    }

    const size_t part = (size_t)b * NCHUNK + c;
#pragma unroll
    for (int mt = 0; mt < 4; ++mt)
#pragma unroll
        for (int nt = 0; nt < 4; ++nt)
#pragma unroll
            for (int r = 0; r < 4; ++r)
                Opart[(part * 64 + mt * 16 + q * 4 + r) * 512 + w * 64 + nt * 16 + c16] = acc[mt][nt][r];
    if (t < 64) {
        ML[part * 128 + t]      = mrow[t];
        ML[part * 128 + 64 + t] = lrow[t];
    }
}

// ---------------- combine chunk partials ------------------------------------
__global__ __launch_bounds__(128) void combine_kernel(const float* __restrict__ Opart,
                                                      const float* __restrict__ ML,
                                                      float* __restrict__ out) {
    const int b = blockIdx.x >> 6, row = blockIdx.x & 63;
    const int t = threadIdx.x;
    float m[NCHUNK], lv[NCHUNK];
    float M = -1e30f;
#pragma unroll
    for (int c = 0; c < NCHUNK; ++c) {
        m[c]  = ML[(size_t)(b * NCHUNK + c) * 128 + row];
        lv[c] = ML[(size_t)(b * NCHUNK + c) * 128 + 64 + row];
        M = fmaxf(M, m[c]);
    }
    float den = 0.f, wgt[NCHUNK];
#pragma unroll
    for (int c = 0; c < NCHUNK; ++c) { wgt[c] = __expf(m[c] - M); den += wgt[c] * lv[c]; }
    float4 o = make_float4(0.f, 0.f, 0.f, 0.f);
#pragma unroll
    for (int c = 0; c < NCHUNK; ++c) {
        float4 v = *(const float4*)&Opart[((size_t)(b * NCHUNK + c) * 64 + row) * 512 + t * 4];
        o.x += wgt[c] * v.x; o.y += wgt[c] * v.y; o.z += wgt[c] * v.z; o.w += wgt[c] * v.w;
    }
    const float inv = 1.f / den;
    float4 res = make_float4(o.x * inv, o.y * inv, o.z * inv, o.w * inv);
    *(float4*)&out[((size_t)(b * 64 + row)) * 512 + t * 4] = res;
}

extern "C" void kernel_launch(void* const* d_in, const int* in_sizes, int n_in,
                              void* d_out, int out_size, void* d_ws, size_t ws_size,
                              hipStream_t stream) {
    const float* x1 = (const float*)d_in[0];   // [32,64,512]
    const float* x2 = (const float*)d_in[1];   // [32,4096,512]
    const float* wq = (const float*)d_in[3];
    const float* bq = (const float*)d_in[4];
    const float* wk = (const float*)d_in[5];
    const float* bk = (const float*)d_in[6];
    const float* wv = (const float*)d_in[7];
    const float* bv = (const float*)d_in[8];
    float* out = (float*)d_out;

    char* ws = (char*)d_ws;
    // x2 half-buffers (dead after proj; Opart/ML alias this region)
    unsigned short* x2h = (unsigned short*)(ws);                 // 67,108,864 B
    unsigned short* x2l = (unsigned short*)(ws + 67108864);      // 67,108,864 B
    float*          Opart = (float*)(ws);                        // 33,554,432 B (aliases x2h)
    float*          ML    = (float*)(ws + 33554432);             // 131,072 B
    unsigned short* k2  = (unsigned short*)(ws + 134217728);     // 268,435,456 B
    unsigned short* vt  = (unsigned short*)(ws + 402653184);     // 134,217,728 B
    unsigned short* q2  = (unsigned short*)(ws + 536870912);     // 4,194,304 B
    unsigned short* x1h = (unsigned short*)(ws + 541065216);     // 2,097,152 B
    unsigned short* x1l = (unsigned short*)(ws + 543162368);     // 2,097,152 B
    unsigned short* wqh = (unsigned short*)(ws + 545259520);
    unsigned short* wql = wqh + 262144;
    unsigned short* wkh = wql + 262144;
    unsigned short* wkl = wkh + 262144;
    unsigned short* wvh = wkl + 262144;
    unsigned short* wvl = wvh + 262144;  // scratch (V is 2-term) — end 548,405,248

    // weight + x1 splits
    split_kernel<<<256, 256, 0, stream>>>(wq, wqh, wql);
    split_kernel<<<256, 256, 0, stream>>>(wk, wkh, wkl);
    split_kernel<<<256, 256, 0, stream>>>(wv, wvh, wvl);
    split_kernel<<<1024, 256, 0, stream>>>(x1, x1h, x1l);

    // Q projection (K-path only: grid.x = 4)
    proj_kernel<<<dim3(4, 16), 256, 0, stream>>>(x1h, x1l, wqh, wql, bq, q2,
                                                 wvh, bv, vt, 0);

    // K/V projections, half-pipelined over x2
    for (int h = 0; h < 2; ++h) {
        split_kernel<<<32768, 256, 0, stream>>>(x2 + (size_t)h * HALF_KEYS * DM, x2h, x2l);
        proj_kernel<<<dim3(8, 512), 256, 0, stream>>>(x2h, x2l, wkh, wkl, bk, k2,
                                                      wvh, bv, vt, h * HALF_KEYS);
    }

    // fused attention + combine
    attn_kernel<<<dim3(NCHUNK, NB), 512, 0, stream>>>(q2, k2, vt, Opart, ML);
    combine_kernel<<<NB * LQ, 128, 0, stream>>>(Opart, ML, out);
}

// Round 4
// 1040.008 us; speedup vs baseline: 3.5774x; 1.0026x over previous
//
#include <hip/hip_runtime.h>
#include <math.h>

// Cross-attention forward, B=32, LQ=64, LKV=4096, D=512, fp32 in/out.
// Round 4:
//   - proj: XCD-aware swizzle. Blocks sharing an A-tile get flat IDs stride-8
//     apart (same XCD under round-robin dispatch) -> A-tile + weights stay in
//     that XCD's L2. Round 3 had the sharers consecutive = 8 different XCDs,
//     4x HBM over-fetch (FETCH 532 MB vs ~140 ideal).
//   - attn: CHUNK 256 (was 512) -> 512 blocks = 2/CU co-residency,
//     __launch_bounds__(512,4); register peak cut (QK acc[4][2]).
// Numerics unchanged from round 3 (passed, absmax 0.0156, 4x margin).

#define LQ 64
#define LKV 4096
#define NB 32
#define DM 512
#define SCALE 22.627416997969522f   // sqrt(512)
#define KEYS_TOTAL (NB * LKV)       // 131072
#define HALF_KEYS 65536
#define NCHUNK 16                   // chunks per batch
#define CHUNK 256                   // keys per attn block
#define PBS 264                     // Pb row stride (ushorts): 16B-aligned rows, even bank spread

typedef __attribute__((ext_vector_type(8))) short bf16x8;
typedef __attribute__((ext_vector_type(4))) float f32x4;
typedef __attribute__((ext_vector_type(8))) unsigned short u16x8;
typedef __attribute__((ext_vector_type(4))) unsigned short u16x4;

__device__ __forceinline__ unsigned short f2bf(float f) {   // RNE fp32->bf16
    unsigned u = __float_as_uint(f);
    u += 0x7fffu + ((u >> 16) & 1u);
    return (unsigned short)(u >> 16);
}
__device__ __forceinline__ float bf2f(unsigned short s) {
    return __uint_as_float(((unsigned)s) << 16);
}
__device__ __forceinline__ void gld16(const void* g, void* l) {
    __builtin_amdgcn_global_load_lds(
        (const __attribute__((address_space(1))) unsigned int*)g,
        (__attribute__((address_space(3))) unsigned int*)l, 16, 0, 0);
}

// ---------------- split: fp32 -> hi/lo bf16, 8 elems/thread -----------------
__global__ __launch_bounds__(256) void split_kernel(const float* __restrict__ src,
                                                    unsigned short* __restrict__ hi,
                                                    unsigned short* __restrict__ lo) {
    size_t idx = ((size_t)blockIdx.x * 256 + threadIdx.x) * 8;
    float4 a = *(const float4*)(src + idx);
    float4 b = *(const float4*)(src + idx + 4);
    float ff[8] = {a.x, a.y, a.z, a.w, b.x, b.y, b.z, b.w};
    u16x8 h, l;
#pragma unroll
    for (int i = 0; i < 8; ++i) {
        h[i] = f2bf(ff[i]);
        l[i] = f2bf(ff[i] - bf2f(h[i]));
    }
    *(u16x8*)(hi + idx) = h;
    *(u16x8*)(lo + idx) = l;
}

// ---------------- merged projection GEMM ------------------------------------
// BM=BN=128, BK=32, 256 thr (4 waves 2x2), 16x16x32 bf16.
// XCD swizzle: flat = by*gx+bx; xcd = flat&7 (round-robin dispatch); within an
// XCD, consecutive j share one bm (A-tile) across all gx bn values.
// bn<4: K-path 3-term -> outK[row*1024 + col] hi, [+512] lo
// bn>=4: V-path 2-term -> outV[dim*KEYS_TOTAL + key] bf16, LDS transpose
__global__ __launch_bounds__(256) void proj_kernel(
        const unsigned short* __restrict__ Xh, const unsigned short* __restrict__ Xl,
        const unsigned short* __restrict__ WKh, const unsigned short* __restrict__ WKl,
        const float* __restrict__ biasK, unsigned short* __restrict__ outK,
        const unsigned short* __restrict__ WVh,
        const float* __restrict__ biasV, unsigned short* __restrict__ outV,
        int key0) {
    __shared__ unsigned short smem[16384];          // 32 KB
    unsigned short* Ah = smem;                      // [128][32]
    unsigned short* Al = smem + 4096;
    unsigned short* Bh = smem + 8192;
    unsigned short* Bl = smem + 12288;

    // XCD-aware remap (requires gridDim.y % 8 == 0)
    const unsigned flat = blockIdx.y * gridDim.x + blockIdx.x;
    const unsigned bmPerX = gridDim.y >> 3;
    const unsigned xcd = flat & 7u, j = flat >> 3;
    const int bm = xcd * bmPerX + j / gridDim.x;
    const int bn = j % gridDim.x;

    const bool kpath = (bn < 4);
    const int bncol = kpath ? bn : (bn - 4);
    const unsigned short* Wh = kpath ? WKh : WVh;

    const int t = threadIdx.x, w = t >> 6, l = t & 63;
    const int wm = (w >> 1) * 64, wn = (w & 1) * 64;
    const int c16 = l & 15, q = l >> 4, q8 = q << 3;
    const int rB = l >> 2, cB = (l & 3) << 3;

    f32x4 acc[4][4];
#pragma unroll
    for (int i = 0; i < 4; ++i)
#pragma unroll
        for (int jj = 0; jj < 4; ++jj) acc[i][jj] = (f32x4){0.f,0.f,0.f,0.f};

    for (int k0 = 0; k0 < DM; k0 += 32) {
#pragma unroll
        for (int jj = 0; jj < 2; ++jj) {
            int r = w * 32 + jj * 16;
            size_t ga = (size_t)(bm * 128 + r + rB) * DM + k0 + cB;
            gld16(Xh + ga, &Ah[r * 32]);
            gld16(Xl + ga, &Al[r * 32]);
            size_t gb = (size_t)(bncol * 128 + r + rB) * DM + k0 + cB;
            gld16(Wh + gb, &Bh[r * 32]);
            if (kpath) gld16(WKl + gb, &Bl[r * 32]);
        }
        __syncthreads();
        bf16x8 ah[4], al[4];
#pragma unroll
        for (int mt = 0; mt < 4; ++mt) {
            ah[mt] = *(const bf16x8*)&Ah[(wm + mt*16 + c16) * 32 + q8];
            al[mt] = *(const bf16x8*)&Al[(wm + mt*16 + c16) * 32 + q8];
        }
#pragma unroll
        for (int nt = 0; nt < 4; ++nt) {
            bf16x8 bh = *(const bf16x8*)&Bh[(wn + nt*16 + c16) * 32 + q8];
#pragma unroll
            for (int mt = 0; mt < 4; ++mt) {
                acc[mt][nt] = __builtin_amdgcn_mfma_f32_16x16x32_bf16(ah[mt], bh, acc[mt][nt], 0, 0, 0);
                acc[mt][nt] = __builtin_amdgcn_mfma_f32_16x16x32_bf16(al[mt], bh, acc[mt][nt], 0, 0, 0);
            }
            if (kpath) {
                bf16x8 bl = *(const bf16x8*)&Bl[(wn + nt*16 + c16) * 32 + q8];
#pragma unroll
                for (int mt = 0; mt < 4; ++mt)
                    acc[mt][nt] = __builtin_amdgcn_mfma_f32_16x16x32_bf16(ah[mt], bl, acc[mt][nt], 0, 0, 0);
            }
        }
        __syncthreads();
    }

    if (kpath) {
#pragma unroll
        for (int mt = 0; mt < 4; ++mt)
#pragma unroll
            for (int nt = 0; nt < 4; ++nt) {
                int col = bncol * 128 + wn + nt * 16 + c16;
                float bia = biasK[col];
#pragma unroll
                for (int r = 0; r < 4; ++r) {
                    size_t row = (size_t)key0 + bm * 128 + wm + mt * 16 + q * 4 + r;
                    float y = acc[mt][nt][r] + bia;
                    unsigned short hi = f2bf(y);
                    outK[row * 1024 + col]       = hi;
                    outK[row * 1024 + 512 + col] = f2bf(y - bf2f(hi));
                }
            }
    } else {
        unsigned short* T = smem;     // [128][128] bf16 = 32 KB
#pragma unroll
        for (int mt = 0; mt < 4; ++mt)
#pragma unroll
            for (int nt = 0; nt < 4; ++nt) {
                int nl = wn + nt * 16 + c16;                // dim (local)
                int ml = wm + mt * 16 + q * 4;              // key (local)
                float bia = biasV[bncol * 128 + nl];
                u16x4 pk;
#pragma unroll
                for (int r = 0; r < 4; ++r) pk[r] = f2bf(acc[mt][nt][r] + bia);
                *(u16x4*)&T[nl * 128 + ml] = pk;
            }
        __syncthreads();
        int n = t >> 1, seg = (t & 1) * 64;
        size_t gb = (size_t)(bncol * 128 + n) * KEYS_TOTAL + (size_t)key0 + bm * 128 + seg;
#pragma unroll
        for (int i = 0; i < 8; ++i)
            *(u16x8*)(outV + gb + i * 8) = *(const u16x8*)&T[n * 128 + seg + i * 8];
    }
}

// ---------------- fused attention: per (chunk, batch), CHUNK=256 ------------
// 512 thr = 8 waves. QK: wave w owns keys [w*32,+32) (acc[4][2]).
// PV: wave w owns dims [w*64,+64) (acc[4][4]).
__global__ __launch_bounds__(512, 4) void attn_kernel(
        const unsigned short* __restrict__ Q2,    // [2048][1024] hi|lo
        const unsigned short* __restrict__ K2,    // [131072][1024] hi|lo
        const unsigned short* __restrict__ Vt,    // [512][131072]
        float* __restrict__ Opart,                // [512][64][512]
        float* __restrict__ ML) {                 // [512][128] (m|l)
    __shared__ char smem_raw[69120];
    unsigned short* Qh = (unsigned short*)smem_raw;            // [64][32]   0..4096
    unsigned short* Ql = (unsigned short*)(smem_raw + 4096);   //            ..8192
    unsigned short* Kh = (unsigned short*)(smem_raw + 8192);   // [256][32]  ..24576
    unsigned short* Kl = (unsigned short*)(smem_raw + 24576);  //            ..40960
    unsigned short* Pb = (unsigned short*)smem_raw;            // [64][264]  0..33792 (aliases Q/K)
    unsigned short* Vb = (unsigned short*)(smem_raw + 33792);  // [512][32]  ..66560
    float* redb = (float*)(smem_raw + 66560);                  // [8][64]    ..68608
    float* mrow = (float*)(smem_raw + 68608);                  // [64]       ..68864
    float* lrow = (float*)(smem_raw + 68864);                  // [64]       ..69120

    const int c = blockIdx.x, b = blockIdx.y;
    const int t = threadIdx.x, w = t >> 6, l = t & 63;
    const int c16 = l & 15, q = l >> 4, q8 = q << 3;
    const int rB = l >> 2, cB = (l & 3) << 3;
    const size_t key0 = (size_t)b * LKV + (size_t)c * CHUNK;

    f32x4 acc[4][2];
#pragma unroll
    for (int i = 0; i < 4; ++i)
#pragma unroll
        for (int jj = 0; jj < 2; ++jj) acc[i][jj] = (f32x4){0.f,0.f,0.f,0.f};

    // ---- QK: S[64 rows][256 keys]
    for (int k0 = 0; k0 < DM; k0 += 32) {
        if (w < 4)
            gld16(Q2 + (size_t)(b * 64 + w * 16 + rB) * 1024 + k0 + cB, &Qh[(w * 16) * 32]);
        else
            gld16(Q2 + (size_t)(b * 64 + (w - 4) * 16 + rB) * 1024 + 512 + k0 + cB, &Ql[((w - 4) * 16) * 32]);
#pragma unroll
        for (int jj = 0; jj < 2; ++jj) {
            int r = w * 32 + jj * 16;
            size_t krow = key0 + r + rB;
            gld16(K2 + krow * 1024 + k0 + cB,       &Kh[r * 32]);
            gld16(K2 + krow * 1024 + 512 + k0 + cB, &Kl[r * 32]);
        }
        __syncthreads();
        bf16x8 ah[4], al[4];
#pragma unroll
        for (int mt = 0; mt < 4; ++mt) {
            ah[mt] = *(const bf16x8*)&Qh[(mt * 16 + c16) * 32 + q8];
            al[mt] = *(const bf16x8*)&Ql[(mt * 16 + c16) * 32 + q8];
        }
#pragma unroll
        for (int nt = 0; nt < 2; ++nt) {
            bf16x8 bh = *(const bf16x8*)&Kh[(w * 32 + nt * 16 + c16) * 32 + q8];
            bf16x8 bl = *(const bf16x8*)&Kl[(w * 32 + nt * 16 + c16) * 32 + q8];
#pragma unroll
            for (int mt = 0; mt < 4; ++mt) {
                acc[mt][nt] = __builtin_amdgcn_mfma_f32_16x16x32_bf16(ah[mt], bh, acc[mt][nt], 0, 0, 0);
                acc[mt][nt] = __builtin_amdgcn_mfma_f32_16x16x32_bf16(al[mt], bh, acc[mt][nt], 0, 0, 0);
                acc[mt][nt] = __builtin_amdgcn_mfma_f32_16x16x32_bf16(ah[mt], bl, acc[mt][nt], 0, 0, 0);
            }
        }
        __syncthreads();
    }

    // ---- softmax over the chunk
#pragma unroll
    for (int mt = 0; mt < 4; ++mt)
#pragma unroll
        for (int nt = 0; nt < 2; ++nt)
#pragma unroll
            for (int r = 0; r < 4; ++r) acc[mt][nt][r] *= SCALE;

    float rmax_[4][4];
#pragma unroll
    for (int mt = 0; mt < 4; ++mt)
#pragma unroll
        for (int r = 0; r < 4; ++r)
            rmax_[mt][r] = fmaxf(acc[mt][0][r], acc[mt][1][r]);
#pragma unroll
    for (int off = 1; off < 16; off <<= 1)
#pragma unroll
        for (int mt = 0; mt < 4; ++mt)
#pragma unroll
            for (int r = 0; r < 4; ++r)
                rmax_[mt][r] = fmaxf(rmax_[mt][r], __shfl_xor(rmax_[mt][r], off));
    if (c16 == 0) {
#pragma unroll
        for (int mt = 0; mt < 4; ++mt)
#pragma unroll
            for (int r = 0; r < 4; ++r) redb[w * 64 + mt * 16 + q * 4 + r] = rmax_[mt][r];
    }
    __syncthreads();
    if (t < 64) {
        float m = redb[t];
#pragma unroll
        for (int ww = 1; ww < 8; ++ww) m = fmaxf(m, redb[ww * 64 + t]);
        mrow[t] = m;
    }
    __syncthreads();

    float rsum_[4][4];
#pragma unroll
    for (int mt = 0; mt < 4; ++mt)
#pragma unroll
        for (int r = 0; r < 4; ++r) {
            float m = mrow[mt * 16 + q * 4 + r];
            float s = 0.f;
#pragma unroll
            for (int nt = 0; nt < 2; ++nt) {
                float e = __expf(acc[mt][nt][r] - m);
                acc[mt][nt][r] = e;
                s += e;
            }
            rsum_[mt][r] = s;
        }
#pragma unroll
    for (int off = 1; off < 16; off <<= 1)
#pragma unroll
        for (int mt = 0; mt < 4; ++mt)
#pragma unroll
            for (int r = 0; r < 4; ++r) rsum_[mt][r] += __shfl_xor(rsum_[mt][r], off);
    if (c16 == 0) {
#pragma unroll
        for (int mt = 0; mt < 4; ++mt)
#pragma unroll
            for (int r = 0; r < 4; ++r) redb[w * 64 + mt * 16 + q * 4 + r] = rsum_[mt][r];
    }
    __syncthreads();
    if (t < 64) {
        float s = redb[t];
#pragma unroll
        for (int ww = 1; ww < 8; ++ww) s += redb[ww * 64 + t];
        lrow[t] = s;
    }
    // P -> LDS (bf16 row-major [row][key], stride PBS)
#pragma unroll
    for (int mt = 0; mt < 4; ++mt)
#pragma unroll
        for (int nt = 0; nt < 2; ++nt)
#pragma unroll
            for (int r = 0; r < 4; ++r)
                Pb[(mt * 16 + q * 4 + r) * PBS + w * 32 + nt * 16 + c16] = f2bf(acc[mt][nt][r]);
    __syncthreads();

    // ---- PV: O[64][512]
    f32x4 accO[4][4];
#pragma unroll
    for (int i = 0; i < 4; ++i)
#pragma unroll
        for (int jj = 0; jj < 4; ++jj) accO[i][jj] = (f32x4){0.f,0.f,0.f,0.f};

    for (int ks = 0; ks < CHUNK; ks += 32) {
#pragma unroll
        for (int jj = 0; jj < 4; ++jj) {
            int d = jj * 128 + w * 16;
            gld16(Vt + (size_t)(d + rB) * KEYS_TOTAL + key0 + ks + cB, &Vb[d * 32]);
        }
        __syncthreads();
        bf16x8 ap[4];
#pragma unroll
        for (int mt = 0; mt < 4; ++mt)
            ap[mt] = *(const bf16x8*)&Pb[(mt * 16 + c16) * PBS + ks + q8];
#pragma unroll
        for (int nt = 0; nt < 4; ++nt) {
            bf16x8 bv = *(const bf16x8*)&Vb[(w * 64 + nt * 16 + c16) * 32 + q8];
#pragma unroll
            for (int mt = 0; mt < 4; ++mt)
                accO[mt][nt] = __builtin_amdgcn_mfma_f32_16x16x32_bf16(ap[mt], bv, accO[mt][nt], 0, 0, 0);
        }
        __syncthreads();
    }

    const size_t part = (size_t)b * NCHUNK + c;
#pragma unroll
    for (int mt = 0; mt < 4; ++mt)
#pragma unroll
        for (int nt = 0; nt < 4; ++nt)
#pragma unroll
            for (int r = 0; r < 4; ++r)
                Opart[(part * 64 + mt * 16 + q * 4 + r) * 512 + w * 64 + nt * 16 + c16] = accO[mt][nt][r];
    if (t < 64) {
        ML[part * 128 + t]      = mrow[t];
        ML[part * 128 + 64 + t] = lrow[t];
    }
}

// ---------------- combine chunk partials ------------------------------------
__global__ __launch_bounds__(128) void combine_kernel(const float* __restrict__ Opart,
                                                      const float* __restrict__ ML,
                                                      float* __restrict__ out) {
    const int b = blockIdx.x >> 6, row = blockIdx.x & 63;
    const int t = threadIdx.x;
    float m[NCHUNK], lv[NCHUNK];
    float M = -1e30f;
#pragma unroll
    for (int c = 0; c < NCHUNK; ++c) {
        m[c]  = ML[(size_t)(b * NCHUNK + c) * 128 + row];
        lv[c] = ML[(size_t)(b * NCHUNK + c) * 128 + 64 + row];
        M = fmaxf(M, m[c]);
    }
    float den = 0.f, wgt[NCHUNK];
#pragma unroll
    for (int c = 0; c < NCHUNK; ++c) { wgt[c] = __expf(m[c] - M); den += wgt[c] * lv[c]; }
    float4 o = make_float4(0.f, 0.f, 0.f, 0.f);
#pragma unroll
    for (int c = 0; c < NCHUNK; ++c) {
        float4 v = *(const float4*)&Opart[((size_t)(b * NCHUNK + c) * 64 + row) * 512 + t * 4];
        o.x += wgt[c] * v.x; o.y += wgt[c] * v.y; o.z += wgt[c] * v.z; o.w += wgt[c] * v.w;
    }
    const float inv = 1.f / den;
    float4 res = make_float4(o.x * inv, o.y * inv, o.z * inv, o.w * inv);
    *(float4*)&out[((size_t)(b * 64 + row)) * 512 + t * 4] = res;
}

extern "C" void kernel_launch(void* const* d_in, const int* in_sizes, int n_in,
                              void* d_out, int out_size, void* d_ws, size_t ws_size,
                              hipStream_t stream) {
    const float* x1 = (const float*)d_in[0];   // [32,64,512]
    const float* x2 = (const float*)d_in[1];   // [32,4096,512]
    const float* wq = (const float*)d_in[3];
    const float* bq = (const float*)d_in[4];
    const float* wk = (const float*)d_in[5];
    const float* bk = (const float*)d_in[6];
    const float* wv = (const float*)d_in[7];
    const float* bv = (const float*)d_in[8];
    float* out = (float*)d_out;

    char* ws = (char*)d_ws;
    // x2 half-buffers (dead after proj; Opart/ML alias this region)
    unsigned short* x2h = (unsigned short*)(ws);                 // 67,108,864 B
    unsigned short* x2l = (unsigned short*)(ws + 67108864);      // 67,108,864 B
    float*          Opart = (float*)(ws);                        // 67,108,864 B (aliases x2h)
    float*          ML    = (float*)(ws + 67108864);             // 262,144 B (aliases x2l)
    unsigned short* k2  = (unsigned short*)(ws + 134217728);     // 268,435,456 B
    unsigned short* vt  = (unsigned short*)(ws + 402653184);     // 134,217,728 B
    unsigned short* q2  = (unsigned short*)(ws + 536870912);     // 4,194,304 B
    unsigned short* x1h = (unsigned short*)(ws + 541065216);     // 2,097,152 B
    unsigned short* x1l = (unsigned short*)(ws + 543162368);     // 2,097,152 B
    unsigned short* wqh = (unsigned short*)(ws + 545259520);
    unsigned short* wql = wqh + 262144;
    unsigned short* wkh = wql + 262144;
    unsigned short* wkl = wkh + 262144;
    unsigned short* wvh = wkl + 262144;
    unsigned short* wvl = wvh + 262144;  // scratch — end 548,405,248

    // weight + x1 splits (8 elems/thread)
    split_kernel<<<128, 256, 0, stream>>>(wq, wqh, wql);
    split_kernel<<<128, 256, 0, stream>>>(wk, wkh, wkl);
    split_kernel<<<128, 256, 0, stream>>>(wv, wvh, wvl);
    split_kernel<<<512, 256, 0, stream>>>(x1, x1h, x1l);

    // Q projection (K-path only: grid.x = 4, gridDim.y=16 divisible by 8)
    proj_kernel<<<dim3(4, 16), 256, 0, stream>>>(x1h, x1l, wqh, wql, bq, q2,
                                                 wvh, bv, vt, 0);

    // K/V projections, half-pipelined over x2
    for (int h = 0; h < 2; ++h) {
        split_kernel<<<16384, 256, 0, stream>>>(x2 + (size_t)h * HALF_KEYS * DM, x2h, x2l);
        proj_kernel<<<dim3(8, 512), 256, 0, stream>>>(x2h, x2l, wkh, wkl, bk, k2,
                                                      wvh, bv, vt, h * HALF_KEYS);
    }

    // fused attention + combine
    attn_kernel<<<dim3(NCHUNK, NB), 512, 0, stream>>>(q2, k2, vt, Opart, ML);
    combine_kernel<<<NB * LQ, 128, 0, stream>>>(Opart, ML, out);
}